// Round 14
// baseline (76.670 us; speedup 1.0000x reference)
//
#include <hip/hip_runtime.h>

#define CI 32
#define CO 32
#define PD 64
#define QDIM 1024
#define M_TOTAL (32*4096)
#define TILE_M 64                  // per WG = per WAVE (R=2: rows l31, l31+32)
#define NBLK (M_TOTAL/TILE_M)      // 2048 single-wave WGs
#define WG_THREADS 64

typedef float  f32x4  __attribute__((ext_vector_type(4)));
typedef float  f32x16 __attribute__((ext_vector_type(16)));
typedef __bf16 bf16x4 __attribute__((ext_vector_type(4)));
typedef __bf16 bf16x8 __attribute__((ext_vector_type(8)));

#define XLS 65     // U.x[i][m]: bank (i+m)%32 -> conflict-free reads & ~2-way writes

// ---- one-time: Wk [64][1024] f32 -> wsF, MFMA-A-fragment-linear layout ----
// wsF elem idx = (q>>5)*2048 + (k>>3)*256 + (q&31)*8 + (k&7)  [bf16]
// per i, frag f, lane (l31,hi) reads contiguous: wsF + i*2048 + (2f+hi)*256 + l31*8
__global__ __launch_bounds__(256)
void wk_pack_kernel(const float* __restrict__ Wk, __bf16* __restrict__ wsF)
{
    __shared__ float tile[64][33];
    const int q0 = blockIdx.x * 32;
    const int t  = threadIdx.x;
#pragma unroll
    for (int s = 0; s < 2; ++s) {
        const int idx = t + s * 256;
        const int k = idx >> 3, ch = idx & 7;
        f32x4 v = *(const f32x4*)(Wk + (size_t)k * QDIM + q0 + ch * 4);
        tile[k][ch*4+0] = v[0]; tile[k][ch*4+1] = v[1];
        tile[k][ch*4+2] = v[2]; tile[k][ch*4+3] = v[3];
    }
    __syncthreads();
    const int qq = t >> 3;          // 0..31
    const int g  = t & 7;           // k-octet
    bf16x8 o;
#pragma unroll
    for (int j = 0; j < 8; ++j) o[j] = (__bf16)tile[g*8 + j][qq];
    *(bf16x8*)(wsF + (size_t)blockIdx.x * 2048 + g * 256 + qq * 8) = o;
}

// SINGLE-WAVE WGs for max TLP: no inter-wave lockstep (R4-R13's shared wall:
// all pipes idle, occupancy <=18%). 8.3 KB LDS (P-tile and X time-share one
// union; P dead after bfrag extraction) -> ~16 waves/CU vs 5 before.
// Proven elements kept: wsF coalesced A (R12), 2-deep prefetch, swizzled P,
// direct 16B stores (lines completed within the wave -> no R2-style RMW).
__global__ __launch_bounds__(WG_THREADS, 4)
void cond_dense_kernel(const float* __restrict__ Xg, const float* __restrict__ Pg,
                       const __bf16* __restrict__ wsF, float* __restrict__ outg)
{
    __shared__ union {
        __bf16 p[TILE_M * PD];     // 8192 B: P-tile (until bfrag extracted)
        float  x[CI * XLS];        // 8320 B: X transposed [i][m] (i-loop)
    } U;

    const int l   = threadIdx.x;   // 0..63
    const int l31 = l & 31;
    const int hi  = l >> 5;        // k-half within K=16 MFMA
    const int tile0 = blockIdx.x * TILE_M;

    // ---- issue all global input loads up front (regs) ----
    f32x4 xr[8];                   // X[64][32] = 512 f32x4 / 64 lanes
    {
        const float* Xb = Xg + (size_t)tile0 * CI;
#pragma unroll
        for (int s = 0; s < 8; ++s) {
            const int id = l + 64 * s;
            xr[s] = *(const f32x4*)(Xb + (size_t)(id >> 3) * CI + (id & 7) * 4);
        }
    }
    f32x4 pr[16];                  // P[64][64] = 1024 f32x4 / 64 lanes
    {
        const float* Pb = Pg + (size_t)tile0 * PD;
#pragma unroll
        for (int s = 0; s < 16; ++s) {
            const int id = l + 64 * s;
            pr[s] = *(const f32x4*)(Pb + (size_t)(id >> 4) * PD + (id & 15) * 4);
        }
    }

    // ---- P -> bf16 swizzled LDS ----
#pragma unroll
    for (int s = 0; s < 16; ++s) {
        const int id = l + 64 * s;
        const int r = id >> 4, ch = id & 15;
        bf16x4 bv;
#pragma unroll
        for (int j = 0; j < 4; ++j) bv[j] = (__bf16)pr[s][j];
        char* dst = (char*)U.p + r * 128
                  + ((((ch >> 1) ^ (r & 7)) << 4) | ((ch & 1) * 8));
        *(bf16x4*)dst = bv;
    }
    __syncthreads();   // 1-wave: lgkmcnt drain, barrier is instant

    // ---- B fragments (P^T) for rows l31 and l31+32 ----
    bf16x8 bfA[4], bfB[4];
#pragma unroll
    for (int kq = 0; kq < 4; ++kq) {
        const int g = ((kq * 2 + hi) ^ (l31 & 7)) << 4;   // (l31+32)&7 == l31&7
        bfA[kq] = *(const bf16x8*)((const char*)U.p + l31 * 128 + g);
        bfB[kq] = *(const bf16x8*)((const char*)U.p + (l31 + 32) * 128 + g);
    }
    __syncthreads();   // bfrag reads retired before U.x overwrites

    // ---- X -> transposed f32 LDS U.x[i][m] ----
#pragma unroll
    for (int s = 0; s < 8; ++s) {
        const int id = l + 64 * s;
        const int r = id >> 3, c = (id & 7) * 4;
#pragma unroll
        for (int j = 0; j < 4; ++j)
            U.x[(c + j) * XLS + r] = xr[s][j];
    }
    __syncthreads();

    // ---- i-loop: coalesced A from wsF (1KB/wave-instr), 2-deep prefetch ----
    f32x16 oA = {}, oB = {};
    const __bf16* abase = wsF + (size_t)hi * 256 + (size_t)l31 * 8;

    bf16x8 a0[4], a1[4];
    auto aload = [&](int i, bf16x8* buf) {
        const __bf16* ap = abase + (size_t)i * 2048;
        buf[0] = *(const bf16x8*)(ap);
        buf[1] = *(const bf16x8*)(ap +  512);
        buf[2] = *(const bf16x8*)(ap + 1024);
        buf[3] = *(const bf16x8*)(ap + 1536);
    };
    auto step = [&](const bf16x8* a, int i) {
        const float xl = U.x[i * XLS + l31];
        const float xh = U.x[i * XLS + l31 + 32];
        f32x16 cA = {}, cB = {};
#pragma unroll
        for (int kq = 0; kq < 4; ++kq) {     // A shared by both row-blocks
            cA = __builtin_amdgcn_mfma_f32_32x32x16_bf16(a[kq], bfA[kq], cA, 0, 0, 0);
            cB = __builtin_amdgcn_mfma_f32_32x32x16_bf16(a[kq], bfB[kq], cB, 0, 0, 0);
        }
#pragma unroll
        for (int r = 0; r < 16; ++r) {
            oA[r] += fmaxf(cA[r], 0.0f) * xl;
            oB[r] += fmaxf(cB[r], 0.0f) * xh;
        }
    };

    aload(0, a0);
    aload(1, a1);
    for (int ii = 0; ii < 16; ++ii) {
        step(a0, 2 * ii);
        if (ii < 15) aload(2 * ii + 2, a0);
        step(a1, 2 * ii + 1);
        if (ii < 15) aload(2 * ii + 3, a1);
    }

    // ---- direct stores: lane row m, o = (r&3)+8*(r>>2)+4*hi ----
    // per rq: f32x4 at col 8*rq+4*hi; each 128B out-row completed by this wave
    {
        float* orow = outg + (size_t)(tile0 + l31) * CO + 4 * hi;
        float* orow2 = orow + 32 * CO;
#pragma unroll
        for (int rq = 0; rq < 4; ++rq) {
            f32x4 vA, vB;
#pragma unroll
            for (int j = 0; j < 4; ++j) { vA[j] = oA[4*rq + j]; vB[j] = oB[4*rq + j]; }
            *(f32x4*)(orow  + 8 * rq) = vA;
            *(f32x4*)(orow2 + 8 * rq) = vB;
        }
    }
}

extern "C" void kernel_launch(void* const* d_in, const int* in_sizes, int n_in,
                              void* d_out, int out_size, void* d_ws, size_t ws_size,
                              hipStream_t stream)
{
    const float* X  = (const float*)d_in[0];
    const float* P  = (const float*)d_in[1];
    const float* Wk = (const float*)d_in[2];
    float* out = (float*)d_out;
    __bf16* wsF = (__bf16*)d_ws;   // 1024*64*2 = 128 KB

    wk_pack_kernel<<<dim3(QDIM / 32), dim3(256), 0, stream>>>(Wk, wsF);
    cond_dense_kernel<<<dim3(NBLK), dim3(WG_THREADS), 0, stream>>>(X, P, wsF, out);
}